// Round 1
// baseline (118.755 us; speedup 1.0000x reference)
//
#include <hip/hip_runtime.h>
#include <hip/hip_bf16.h>

// Problem constants (match reference setup_inputs)
#define BATCH 8
#define CHN   64
#define GRP   8
#define CG    8      // CHN / GRP
#define HH    128
#define WW    128
// w shape: (B, G, 1, 9, H, W); x/out shape: (B, C, H, W), all fp32.

__global__ __launch_bounds__(256) void ska_small_kernel(
    const float* __restrict__ x,
    const float* __restrict__ wgt,
    float* __restrict__ out)
{
    // Thread mapping: tid bits = [b:3][g:3][h:7][wquad:5]  (total 2^18 threads)
    int tid = blockIdx.x * blockDim.x + threadIdx.x;
    int w0 = (tid & 31) * 4;          // 0..124, aligned float4 column
    int h  = (tid >> 5) & 127;
    int g  = (tid >> 12) & 7;
    int b  = tid >> 15;

    const size_t HW = (size_t)HH * WW;

    // ---- Load the 9 dynamic weights for this pixel-quad (shared across CG channels)
    const float* wbase = wgt + ((size_t)(b * GRP + g) * 9) * HW + (size_t)h * WW + w0;
    float4 wk[9];
#pragma unroll
    for (int k = 0; k < 9; ++k) {
        wk[k] = *(const float4*)(wbase + (size_t)k * HW);
    }

    const float* xbase = x   + (size_t)(b * CHN + g * CG) * HW;
    float*       obase = out + (size_t)(b * CHN + g * CG) * HW;

    const bool h_lo = (h > 0);
    const bool h_hi = (h < HH - 1);
    const bool w_lo = (w0 > 0);
    const bool w_hi = (w0 + 4 < WW);

#pragma unroll
    for (int cg = 0; cg < CG; ++cg) {
        const float* xc = xbase + (size_t)cg * HW + (size_t)h * WW + w0;

        // three input rows (h-1, h, h+1), columns w0-1 .. w0+4
        float xr[3][6];
#pragma unroll
        for (int r = 0; r < 3; ++r) {
            bool ok = (r == 0) ? h_lo : (r == 2) ? h_hi : true;
            const float* xrow = xc + (ptrdiff_t)(r - 1) * WW;
            if (ok) {
                float4 v = *(const float4*)xrow;
                xr[r][1] = v.x; xr[r][2] = v.y; xr[r][3] = v.z; xr[r][4] = v.w;
                xr[r][0] = w_lo ? xrow[-1] : 0.0f;
                xr[r][5] = w_hi ? xrow[4]  : 0.0f;
            } else {
#pragma unroll
                for (int j = 0; j < 6; ++j) xr[r][j] = 0.0f;
            }
        }

        float4 acc = make_float4(0.f, 0.f, 0.f, 0.f);
#pragma unroll
        for (int ki = 0; ki < 3; ++ki) {
#pragma unroll
            for (int kj = 0; kj < 3; ++kj) {
                const float4 wv = wk[ki * 3 + kj];
                acc.x = fmaf(xr[ki][0 + kj], wv.x, acc.x);
                acc.y = fmaf(xr[ki][1 + kj], wv.y, acc.y);
                acc.z = fmaf(xr[ki][2 + kj], wv.z, acc.z);
                acc.w = fmaf(xr[ki][3 + kj], wv.w, acc.w);
            }
        }

        *(float4*)(obase + (size_t)cg * HW + (size_t)h * WW + w0) = acc;
    }
}

extern "C" void kernel_launch(void* const* d_in, const int* in_sizes, int n_in,
                              void* d_out, int out_size, void* d_ws, size_t ws_size,
                              hipStream_t stream) {
    const float* x = (const float*)d_in[0];
    const float* w = (const float*)d_in[1];
    float* out = (float*)d_out;

    // total threads = B * G * H * (W/4) = 8*8*128*32 = 262144
    const int total = BATCH * GRP * HH * (WW / 4);
    const int block = 256;
    const int grid = total / block;   // 1024
    ska_small_kernel<<<grid, block, 0, stream>>>(x, w, out);
}

// Round 2
// 105.588 us; speedup vs baseline: 1.1247x; 1.1247x over previous
//
#include <hip/hip_runtime.h>
#include <hip/hip_bf16.h>

// Problem constants (match reference setup_inputs)
#define BATCH 8
#define CHN   64
#define GRP   8
#define CG    8      // CHN / GRP
#define HH    128
#define WW    128
#define HW    (HH * WW)   // 16384
// w shape: (B, G, 1, 9, H, W); x/out shape: (B, C, H, W), all fp32.

__global__ __launch_bounds__(256, 4) void ska_small_kernel(
    const float* __restrict__ x,
    const float* __restrict__ wgt,
    float* __restrict__ out)
{
    // Thread mapping: tid bits = [b:3][g:3][h:7][wquad:5]  (total 2^18 threads)
    // A wave's 64 lanes cover 2 consecutive image rows x 32 quads -> all global
    // accesses are contiguous 1 KiB per wave instruction.
    int tid = blockIdx.x * blockDim.x + threadIdx.x;
    int q  = tid & 31;          // quad index within row
    int w0 = q * 4;             // aligned float4 column
    int h  = (tid >> 5) & 127;
    int g  = (tid >> 12) & 7;
    int b  = tid >> 15;

    // ---- 9 dynamic weights for this pixel-quad (shared across CG channels)
    const float* wbase = wgt + ((size_t)(b * GRP + g) * 9) * HW + (size_t)h * WW + w0;
    float4 wk[9];
#pragma unroll
    for (int k = 0; k < 9; ++k) {
        wk[k] = *(const float4*)(wbase + (size_t)k * HW);
    }

    // Fold vertical zero-padding into the weights (branchless):
    // tap row 0 contributes 0 at h==0, tap row 2 contributes 0 at h==127.
    const float m_top = (h > 0)      ? 1.0f : 0.0f;
    const float m_bot = (h < HH - 1) ? 1.0f : 0.0f;
#pragma unroll
    for (int j = 0; j < 3; ++j) {
        wk[j].x     *= m_top; wk[j].y     *= m_top; wk[j].z     *= m_top; wk[j].w     *= m_top;
        wk[6 + j].x *= m_bot; wk[6 + j].y *= m_bot; wk[6 + j].z *= m_bot; wk[6 + j].w *= m_bot;
    }

    // Horizontal halo comes from neighbor lanes via shuffle; mask pad columns.
    const float mL = (q > 0)  ? 1.0f : 0.0f;
    const float mR = (q < 31) ? 1.0f : 0.0f;

    // Clamped row indices (out-of-range rows are weight-masked to zero).
    const int hm = (h > 0)      ? h - 1 : h;
    const int hp = (h < HH - 1) ? h + 1 : h;

    const float* xbase = x   + (size_t)(b * CHN + g * CG) * HW + w0;
    float*       obase = out + (size_t)(b * CHN + g * CG) * HW + (size_t)h * WW + w0;

#pragma unroll
    for (int cg = 0; cg < CG; ++cg) {
        const float* xc = xbase + (size_t)cg * HW;
        float4 r0 = *(const float4*)(xc + (size_t)hm * WW);
        float4 r1 = *(const float4*)(xc + (size_t)h  * WW);
        float4 r2 = *(const float4*)(xc + (size_t)hp * WW);

        // 6-wide row windows: [left, v.x, v.y, v.z, v.w, right]
        float xr[3][6];
        xr[0][1] = r0.x; xr[0][2] = r0.y; xr[0][3] = r0.z; xr[0][4] = r0.w;
        xr[1][1] = r1.x; xr[1][2] = r1.y; xr[1][3] = r1.z; xr[1][4] = r1.w;
        xr[2][1] = r2.x; xr[2][2] = r2.y; xr[2][3] = r2.z; xr[2][4] = r2.w;
        xr[0][0] = __shfl_up(r0.w, 1) * mL;
        xr[1][0] = __shfl_up(r1.w, 1) * mL;
        xr[2][0] = __shfl_up(r2.w, 1) * mL;
        xr[0][5] = __shfl_down(r0.x, 1) * mR;
        xr[1][5] = __shfl_down(r1.x, 1) * mR;
        xr[2][5] = __shfl_down(r2.x, 1) * mR;

        float4 acc = make_float4(0.f, 0.f, 0.f, 0.f);
#pragma unroll
        for (int ki = 0; ki < 3; ++ki) {
#pragma unroll
            for (int kj = 0; kj < 3; ++kj) {
                const float4 wv = wk[ki * 3 + kj];
                acc.x = fmaf(xr[ki][0 + kj], wv.x, acc.x);
                acc.y = fmaf(xr[ki][1 + kj], wv.y, acc.y);
                acc.z = fmaf(xr[ki][2 + kj], wv.z, acc.z);
                acc.w = fmaf(xr[ki][3 + kj], wv.w, acc.w);
            }
        }

        *(float4*)(obase + (size_t)cg * HW) = acc;
    }
}

extern "C" void kernel_launch(void* const* d_in, const int* in_sizes, int n_in,
                              void* d_out, int out_size, void* d_ws, size_t ws_size,
                              hipStream_t stream) {
    const float* x = (const float*)d_in[0];
    const float* w = (const float*)d_in[1];
    float* out = (float*)d_out;

    // total threads = B * G * H * (W/4) = 8*8*128*32 = 262144
    const int total = BATCH * GRP * HH * (WW / 4);
    const int block = 256;
    const int grid = total / block;   // 1024
    ska_small_kernel<<<grid, block, 0, stream>>>(x, w, out);
}